// Round 1
// baseline (696.936 us; speedup 1.0000x reference)
//
#include <hip/hip_runtime.h>
#include <hip/hip_fp16.h>

#define MKEY 256        // K (key size)
#define NMEM 100000     // memory rows
#define NPAD 100096     // 782 * 128
#define NQ   2048       // queries
#define BM 128
#define BN 128
#define BK 64
#define NTILES 782      // NPAD / BN
#define MTILES 16       // NQ / BM

typedef _Float16 f16x8 __attribute__((ext_vector_type(8)));
typedef float f32x4 __attribute__((ext_vector_type(4)));

__device__ inline unsigned ord_f32(float f) {
  unsigned b = __float_as_uint(f);
  return (b & 0x80000000u) ? ~b : (b | 0x80000000u);
}

__device__ inline void gll16(const void* g, void* l) {
  __builtin_amdgcn_global_load_lds(
      (const __attribute__((address_space(1))) unsigned*)g,
      (__attribute__((address_space(3))) unsigned*)l, 16, 0, 0);
}

__global__ void init_best(unsigned long long* best) {
  best[blockIdx.x * 256 + threadIdx.x] = 0ull;
}

// split query fp32 -> fp16 hi/lo limbs
__global__ void conv_query(const float* __restrict__ q,
                           unsigned short* __restrict__ qh,
                           unsigned short* __restrict__ ql) {
  const int i = blockIdx.x * 256 + threadIdx.x;
  float x = q[i];
  __half hh = __float2half(x);
  qh[i] = __half_as_ushort(hh);
  ql[i] = __half_as_ushort(__float2half(x - __half2float(hh)));
}

// split keys fp32 -> fp16 hi/lo limbs + inv key norm; zero-fill pad rows
__global__ void conv_keys(const float* __restrict__ mem,
                          unsigned short* __restrict__ kh,
                          unsigned short* __restrict__ kl,
                          float* __restrict__ rkn) {
  const int t = threadIdx.x, lane = t & 63, w = t >> 6;
  const int row = blockIdx.x * 4 + w;
  if (row < NMEM) {
    const float4 v = *(const float4*)&mem[(long)row * 512 + lane * 4];
    float fs[4] = {v.x, v.y, v.z, v.w};
    unsigned short hb[4], lb[4];
    float ss = 0.f;
#pragma unroll
    for (int c = 0; c < 4; ++c) {
      float x = fs[c];
      ss += x * x;
      __half hh = __float2half(x);
      hb[c] = __half_as_ushort(hh);
      lb[c] = __half_as_ushort(__float2half(x - __half2float(hh)));
    }
    *(ushort4*)&kh[(long)row * 256 + lane * 4] = make_ushort4(hb[0], hb[1], hb[2], hb[3]);
    *(ushort4*)&kl[(long)row * 256 + lane * 4] = make_ushort4(lb[0], lb[1], lb[2], lb[3]);
#pragma unroll
    for (int off = 32; off >= 1; off >>= 1) ss += __shfl_xor(ss, off, 64);
    if (lane == 0) rkn[row] = 1.0f / sqrtf(fmaxf(ss, 1e-30f));
  } else {
    *(ushort4*)&kh[(long)row * 256 + lane * 4] = make_ushort4(0, 0, 0, 0);
    *(ushort4*)&kl[(long)row * 256 + lane * 4] = make_ushort4(0, 0, 0, 0);
    if (lane == 0) rkn[row] = 0.f;
  }
}

// fused fp32-via-fp16x2 GEMM + per-query argmax over this block's N-tile
__global__ __launch_bounds__(256, 2) void gemm_argmax(
    const unsigned short* __restrict__ qh, const unsigned short* __restrict__ ql,
    const unsigned short* __restrict__ kh, const unsigned short* __restrict__ kl,
    const float* __restrict__ rkn, unsigned long long* __restrict__ best) {
  __shared__ unsigned short Ah[BM * BK], Al[BM * BK], Bh[BN * BK], Bl[BN * BK];
  __shared__ unsigned long long cand[BM][2];

  const int t = threadIdx.x;
  const int w = t >> 6;         // wave 0..3
  const int lane = t & 63;
  const int mtile = blockIdx.x; // 0..15
  const int ntile = blockIdx.y; // 0..781
  const int wr = w >> 1, wc = w & 1;
  const int q16 = lane >> 4, l16 = lane & 15;

  f32x4 acc[4][4];
#pragma unroll
  for (int i = 0; i < 4; i++)
#pragma unroll
    for (int j = 0; j < 4; j++) acc[i][j] = (f32x4){0.f, 0.f, 0.f, 0.f};

  const int srow = lane >> 3;      // 0..7
  const int scol = (lane & 7) * 8; // element col for staging
  const long aBase = (long)(mtile * BM) * MKEY;
  const long bBase = (long)(ntile * BN) * MKEY;

  for (int k0 = 0; k0 < MKEY; k0 += BK) {
    __syncthreads();
#pragma unroll
    for (int c = 0; c < 4; ++c) {
      const int r = w * 8 + 32 * c + srow;             // tile row 0..127
      const long ga = aBase + (long)r * MKEY + k0 + scol;
      const long gb = bBase + (long)r * MKEY + k0 + scol;
      const int lofs = (w * 8 + 32 * c) * BK;          // wave-uniform LDS base
      gll16(qh + ga, &Ah[lofs]);
      gll16(ql + ga, &Al[lofs]);
      gll16(kh + gb, &Bh[lofs]);
      gll16(kl + gb, &Bl[lofs]);
    }
    __syncthreads();  // drains vmcnt -> LDS visible
#pragma unroll
    for (int ks = 0; ks < 2; ++ks) {
      const int kofs = ks * 32 + q16 * 8;
      f16x8 ah[4], al[4], bh[4], bl[4];
#pragma unroll
      for (int i = 0; i < 4; i++) {
        ah[i] = *(const f16x8*)&Ah[(64 * wr + 16 * i + l16) * BK + kofs];
        al[i] = *(const f16x8*)&Al[(64 * wr + 16 * i + l16) * BK + kofs];
      }
#pragma unroll
      for (int j = 0; j < 4; j++) {
        bh[j] = *(const f16x8*)&Bh[(64 * wc + 16 * j + l16) * BK + kofs];
        bl[j] = *(const f16x8*)&Bl[(64 * wc + 16 * j + l16) * BK + kofs];
      }
#pragma unroll
      for (int i = 0; i < 4; i++)
#pragma unroll
        for (int j = 0; j < 4; j++) {
          acc[i][j] = __builtin_amdgcn_mfma_f32_16x16x32_f16(ah[i], bh[j], acc[i][j], 0, 0, 0);
          acc[i][j] = __builtin_amdgcn_mfma_f32_16x16x32_f16(ah[i], bl[j], acc[i][j], 0, 0, 0);
          acc[i][j] = __builtin_amdgcn_mfma_f32_16x16x32_f16(al[i], bh[j], acc[i][j], 0, 0, 0);
        }
    }
  }

  // Epilogue: sim = dot * (1/kn); argmax with packed (ordered_sim<<32)|~idx
  int ncol[4];
  float rk[4];
#pragma unroll
  for (int j = 0; j < 4; j++) {
    ncol[j] = ntile * BN + 64 * wc + 16 * j + l16;
    rk[j] = (ncol[j] < NMEM) ? rkn[ncol[j]] : 0.f;
  }
#pragma unroll
  for (int i = 0; i < 4; i++) {
#pragma unroll
    for (int r = 0; r < 4; r++) {
      unsigned long long bp = 0ull;
#pragma unroll
      for (int j = 0; j < 4; j++) {
        if (ncol[j] < NMEM) {
          float s = acc[i][j][r] * rk[j];
          unsigned long long p =
              ((unsigned long long)ord_f32(s) << 32) | (unsigned)(~(unsigned)ncol[j]);
          bp = (p > bp) ? p : bp;
        }
      }
#pragma unroll
      for (int off = 1; off < 16; off <<= 1) {
        unsigned long long o = __shfl_xor(bp, off, 64);
        bp = (o > bp) ? o : bp;
      }
      if (l16 == 0) cand[64 * wr + 16 * i + 4 * q16 + r][wc] = bp;
    }
  }
  __syncthreads();
  if (t < BM) {
    unsigned long long a = cand[t][0], b = cand[t][1];
    unsigned long long m = (a > b) ? a : b;
    atomicMax(&best[mtile * BM + t], m);
  }
}

__global__ void gather_vals(const unsigned long long* __restrict__ best,
                            const float* __restrict__ mem, float* __restrict__ out) {
  const int b = blockIdx.x, lane = threadIdx.x; // 64 threads
  const unsigned idx = ~(unsigned)(best[b] & 0xFFFFFFFFull);
  const float4 v = *(const float4*)&mem[(long)idx * 512 + 256 + lane * 4];
  *(float4*)&out[(long)b * 256 + lane * 4] = v;
}

extern "C" void kernel_launch(void* const* d_in, const int* in_sizes, int n_in,
                              void* d_out, int out_size, void* d_ws, size_t ws_size,
                              hipStream_t stream) {
  const float* query = (const float*)d_in[0];
  const float* memory = (const float*)d_in[1];
  float* out = (float*)d_out;

  char* p = (char*)d_ws;
  unsigned short* qh = (unsigned short*)p; p += (size_t)NQ * MKEY * 2;
  unsigned short* ql = (unsigned short*)p; p += (size_t)NQ * MKEY * 2;
  unsigned short* kh = (unsigned short*)p; p += (size_t)NPAD * MKEY * 2;
  unsigned short* kl = (unsigned short*)p; p += (size_t)NPAD * MKEY * 2;
  float* rkn = (float*)p; p += (size_t)NPAD * 4;
  unsigned long long* best = (unsigned long long*)p; p += (size_t)NQ * 8;

  hipLaunchKernelGGL(init_best, dim3(NQ / 256), dim3(256), 0, stream, best);
  hipLaunchKernelGGL(conv_query, dim3(NQ), dim3(256), 0, stream, query, qh, ql);
  hipLaunchKernelGGL(conv_keys, dim3(NPAD / 4), dim3(256), 0, stream, memory, kh, kl, rkn);
  hipLaunchKernelGGL(gemm_argmax, dim3(MTILES, NTILES), dim3(256), 0, stream,
                     qh, ql, kh, kl, rkn, best);
  hipLaunchKernelGGL(gather_vals, dim3(NQ), dim3(64), 0, stream, best, memory, out);
}

// Round 2
// 675.744 us; speedup vs baseline: 1.0314x; 1.0314x over previous
//
#include <hip/hip_runtime.h>
#include <hip/hip_fp16.h>

#define MKEY 256        // K (key size)
#define NMEM 100000     // memory rows
#define NPAD 100096     // 782 * 128
#define NQ   2048       // queries
#define BM 128
#define BN 128
#define BK 64
#define LDK 72          // padded LDS row stride in halfwords (144 B = 9 x 16B chunks)
#define NTILES 782      // NPAD / BN
#define MTILES 16       // NQ / BM

typedef _Float16 f16x8 __attribute__((ext_vector_type(8)));
typedef float f32x4 __attribute__((ext_vector_type(4)));

__device__ inline unsigned ord_f32(float f) {
  unsigned b = __float_as_uint(f);
  return (b & 0x80000000u) ? ~b : (b | 0x80000000u);
}

__device__ inline void gll16(const void* g, void* l) {
  __builtin_amdgcn_global_load_lds(
      (const __attribute__((address_space(1))) unsigned*)g,
      (__attribute__((address_space(3))) unsigned*)l, 16, 0, 0);
}

__global__ void init_best(unsigned long long* best) {
  best[blockIdx.x * 256 + threadIdx.x] = 0ull;
}

// split query fp32 -> fp16 hi/lo limbs
__global__ void conv_query(const float* __restrict__ q,
                           unsigned short* __restrict__ qh,
                           unsigned short* __restrict__ ql) {
  const int i = blockIdx.x * 256 + threadIdx.x;
  float x = q[i];
  __half hh = __float2half(x);
  qh[i] = __half_as_ushort(hh);
  ql[i] = __half_as_ushort(__float2half(x - __half2float(hh)));
}

// split keys fp32 -> fp16 hi/lo limbs + inv key norm; zero-fill pad rows
__global__ void conv_keys(const float* __restrict__ mem,
                          unsigned short* __restrict__ kh,
                          unsigned short* __restrict__ kl,
                          float* __restrict__ rkn) {
  const int t = threadIdx.x, lane = t & 63, w = t >> 6;
  const int row = blockIdx.x * 4 + w;
  if (row < NMEM) {
    const float4 v = *(const float4*)&mem[(long)row * 512 + lane * 4];
    float fs[4] = {v.x, v.y, v.z, v.w};
    unsigned short hb[4], lb[4];
    float ss = 0.f;
#pragma unroll
    for (int c = 0; c < 4; ++c) {
      float x = fs[c];
      ss += x * x;
      __half hh = __float2half(x);
      hb[c] = __half_as_ushort(hh);
      lb[c] = __half_as_ushort(__float2half(x - __half2float(hh)));
    }
    *(ushort4*)&kh[(long)row * 256 + lane * 4] = make_ushort4(hb[0], hb[1], hb[2], hb[3]);
    *(ushort4*)&kl[(long)row * 256 + lane * 4] = make_ushort4(lb[0], lb[1], lb[2], lb[3]);
#pragma unroll
    for (int off = 32; off >= 1; off >>= 1) ss += __shfl_xor(ss, off, 64);
    if (lane == 0) rkn[row] = 1.0f / sqrtf(fmaxf(ss, 1e-30f));
  } else {
    *(ushort4*)&kh[(long)row * 256 + lane * 4] = make_ushort4(0, 0, 0, 0);
    *(ushort4*)&kl[(long)row * 256 + lane * 4] = make_ushort4(0, 0, 0, 0);
    if (lane == 0) rkn[row] = 0.f;
  }
}

// fused fp32-via-fp16x2 GEMM + per-query argmax over this block's N-tile
__global__ __launch_bounds__(256, 2) void gemm_argmax(
    const unsigned short* __restrict__ qh, const unsigned short* __restrict__ ql,
    const unsigned short* __restrict__ kh, const unsigned short* __restrict__ kl,
    const float* __restrict__ rkn, unsigned long long* __restrict__ best) {
  // padded layout: row stride LDK=72 halfwords (9 x 16B chunks; chunk 8 is pad)
  __shared__ unsigned short Ah[BM * LDK], Al[BM * LDK], Bh[BN * LDK], Bl[BN * LDK];
  __shared__ unsigned long long cand[BM][2];

  const int t = threadIdx.x;
  const int w = t >> 6;         // wave 0..3
  const int lane = t & 63;
  const int mtile = blockIdx.x; // 0..15
  const int ntile = blockIdx.y; // 0..781
  const int wr = w >> 1, wc = w & 1;
  const int q16 = lane >> 4, l16 = lane & 15;

  f32x4 acc[4][4];
#pragma unroll
  for (int i = 0; i < 4; i++)
#pragma unroll
    for (int j = 0; j < 4; j++) acc[i][j] = (f32x4){0.f, 0.f, 0.f, 0.f};

  // staging: wave w owns one array; 18 calls cover 128 rows x 9 chunks
  const unsigned short* gsrc = (w == 0) ? qh : (w == 1) ? ql : (w == 2) ? kh : kl;
  unsigned short* lbuf = (w == 0) ? Ah : (w == 1) ? Al : (w == 2) ? Bh : Bl;
  const long gbase = (w < 2) ? (long)(mtile * BM) * MKEY : (long)(ntile * BN) * MKEY;

  for (int k0 = 0; k0 < MKEY; k0 += BK) {
    __syncthreads();
#pragma unroll
    for (int c = 0; c < 18; ++c) {
      const int slot = c * 64 + lane;      // 0..1151
      const int r = slot / 9;              // row 0..127
      int ch = slot - r * 9;               // chunk 0..8
      if (ch == 8) ch = 0;                 // pad chunk -> dummy load (L1 hit)
      gll16(gsrc + gbase + (long)r * MKEY + k0 + ch * 8, &lbuf[c * 512]);
    }
    __syncthreads();  // drains vmcnt -> LDS visible
#pragma unroll
    for (int ks = 0; ks < 2; ++ks) {
      const int kofs = ks * 32 + q16 * 8;
      f16x8 ah[4], al[4], bh[4], bl[4];
#pragma unroll
      for (int i = 0; i < 4; i++) {
        ah[i] = *(const f16x8*)&Ah[(64 * wr + 16 * i + l16) * LDK + kofs];
        al[i] = *(const f16x8*)&Al[(64 * wr + 16 * i + l16) * LDK + kofs];
      }
#pragma unroll
      for (int j = 0; j < 4; j++) {
        bh[j] = *(const f16x8*)&Bh[(64 * wc + 16 * j + l16) * LDK + kofs];
        bl[j] = *(const f16x8*)&Bl[(64 * wc + 16 * j + l16) * LDK + kofs];
      }
#pragma unroll
      for (int i = 0; i < 4; i++)
#pragma unroll
        for (int j = 0; j < 4; j++) {
          acc[i][j] = __builtin_amdgcn_mfma_f32_16x16x32_f16(ah[i], bh[j], acc[i][j], 0, 0, 0);
          acc[i][j] = __builtin_amdgcn_mfma_f32_16x16x32_f16(ah[i], bl[j], acc[i][j], 0, 0, 0);
          acc[i][j] = __builtin_amdgcn_mfma_f32_16x16x32_f16(al[i], bh[j], acc[i][j], 0, 0, 0);
        }
    }
  }

  // Epilogue: sim = dot * (1/kn); argmax with packed (ordered_sim<<32)|~idx
  int ncol[4];
  float rk[4];
#pragma unroll
  for (int j = 0; j < 4; j++) {
    ncol[j] = ntile * BN + 64 * wc + 16 * j + l16;
    rk[j] = (ncol[j] < NMEM) ? rkn[ncol[j]] : 0.f;
  }
#pragma unroll
  for (int i = 0; i < 4; i++) {
#pragma unroll
    for (int r = 0; r < 4; r++) {
      unsigned long long bp = 0ull;
#pragma unroll
      for (int j = 0; j < 4; j++) {
        if (ncol[j] < NMEM) {
          float s = acc[i][j][r] * rk[j];
          unsigned long long p =
              ((unsigned long long)ord_f32(s) << 32) | (unsigned)(~(unsigned)ncol[j]);
          bp = (p > bp) ? p : bp;
        }
      }
#pragma unroll
      for (int off = 1; off < 16; off <<= 1) {
        unsigned long long o = __shfl_xor(bp, off, 64);
        bp = (o > bp) ? o : bp;
      }
      if (l16 == 0) cand[64 * wr + 16 * i + 4 * q16 + r][wc] = bp;
    }
  }
  __syncthreads();
  if (t < BM) {
    unsigned long long a = cand[t][0], b = cand[t][1];
    unsigned long long m = (a > b) ? a : b;
    atomicMax(&best[mtile * BM + t], m);
  }
}

__global__ void gather_vals(const unsigned long long* __restrict__ best,
                            const float* __restrict__ mem, float* __restrict__ out) {
  const int b = blockIdx.x, lane = threadIdx.x; // 64 threads
  const unsigned idx = ~(unsigned)(best[b] & 0xFFFFFFFFull);
  const float4 v = *(const float4*)&mem[(long)idx * 512 + 256 + lane * 4];
  *(float4*)&out[(long)b * 256 + lane * 4] = v;
}

extern "C" void kernel_launch(void* const* d_in, const int* in_sizes, int n_in,
                              void* d_out, int out_size, void* d_ws, size_t ws_size,
                              hipStream_t stream) {
  const float* query = (const float*)d_in[0];
  const float* memory = (const float*)d_in[1];
  float* out = (float*)d_out;

  char* p = (char*)d_ws;
  unsigned short* qh = (unsigned short*)p; p += (size_t)NQ * MKEY * 2;
  unsigned short* ql = (unsigned short*)p; p += (size_t)NQ * MKEY * 2;
  unsigned short* kh = (unsigned short*)p; p += (size_t)NPAD * MKEY * 2;
  unsigned short* kl = (unsigned short*)p; p += (size_t)NPAD * MKEY * 2;
  float* rkn = (float*)p; p += (size_t)NPAD * 4;
  unsigned long long* best = (unsigned long long*)p; p += (size_t)NQ * 8;

  hipLaunchKernelGGL(init_best, dim3(NQ / 256), dim3(256), 0, stream, best);
  hipLaunchKernelGGL(conv_query, dim3(NQ), dim3(256), 0, stream, query, qh, ql);
  hipLaunchKernelGGL(conv_keys, dim3(NPAD / 4), dim3(256), 0, stream, memory, kh, kl, rkn);
  hipLaunchKernelGGL(gemm_argmax, dim3(MTILES, NTILES), dim3(256), 0, stream,
                     qh, ql, kh, kl, rkn, best);
  hipLaunchKernelGGL(gather_vals, dim3(NQ), dim3(64), 0, stream, best, memory, out);
}